// Round 11
// baseline (120.674 us; speedup 1.0000x reference)
//
#include <hip/hip_runtime.h>

typedef __attribute__((ext_vector_type(8))) short short8;   // 8 bf16 = 4 VGPRs
typedef __attribute__((ext_vector_type(4))) float f32x4;

#define THREADS 256
#define WPB 4            // waves per block = images per block
#define N_PATCH 196
#define NCLS 10
#define FEAT 784
#define ROWSH 40         // ushorts per LDS row = 80 B (20 dwords: period-8 bank pattern, 16B-aligned)

union I4S8 { int i[4]; short8 v; };

__global__ __launch_bounds__(THREADS, 8)   // pin VGPR<=64 -> 8 waves/SIMD ceiling
void quanv_mfma_kernel(const float* __restrict__ x,
                       const float* __restrict__ U,
                       const float* __restrict__ W,
                       const float* __restrict__ b,
                       float* __restrict__ out, int n_img)
{
    // [wave][local patch 0..63][k 0..31 bf16 (+pad)]  k = [hi(d0..15) | lo(d0..15)]
    __shared__ unsigned short sB[WPB][64][ROWSH];      // 20 KB/block -> 8 blocks/CU

    const int t    = threadIdx.x;
    const int w    = t >> 6;
    const int lane = t & 63;
    const int img  = blockIdx.x * WPB + w;
    if (img >= n_img) return;                 // no barriers anywhere in kernel

    const int colc = lane & 15;               // MFMA column (patch-in-group) / A row owner
    const int kb   = lane >> 4;               // k-block 0..3
    const float sgn0 = (kb & 2) ? -1.f : 1.f; // sign of e bit3 (wire 0, MSB): e = 4*kb+reg
    const float sgn1 = (kb & 1) ? -1.f : 1.f; // sign of e bit2 (wire 1)

    // ---- A fragments from U, loaded ONCE ----
    // A1 = [Uhi | Uhi], A2 = [Ulo | 0]  (16x32 each, K-blocked by lane>>4)
    short8 a1, a2;
    {
        const float* Urow = U + colc * 16 + (kb & 1) * 8;
        unsigned ub[8]; float uf[8];
#pragma unroll
        for (int i = 0; i < 8; ++i) { uf[i] = Urow[i]; ub[i] = __float_as_uint(uf[i]); }
        I4S8 hi, lo;
#pragma unroll
        for (int j = 0; j < 4; ++j)
            hi.i[j] = (int)__builtin_amdgcn_perm(ub[2*j+1], ub[2*j], 0x07060302u);
#pragma unroll
        for (int j = 0; j < 4; ++j) {
            unsigned lb0 = __float_as_uint(uf[2*j]   - __uint_as_float(ub[2*j]   & 0xffff0000u));
            unsigned lb1 = __float_as_uint(uf[2*j+1] - __uint_as_float(ub[2*j+1] & 0xffff0000u));
            lo.i[j] = (kb < 2) ? (int)__builtin_amdgcn_perm(lb1, lb0, 0x07060302u) : 0;
        }
        a1 = hi.v; a2 = lo.v;
    }

    const float* ximg = x + (size_t)img * FEAT;

    float acc[NCLS];
#pragma unroll
    for (int c = 0; c < NCLS; ++c) acc[c] = 0.f;

    // 1-deep pixel prefetch (global latency hides under previous iteration)
    float2 top, bot;
    {
        const int r = lane / 14, cl = lane - r * 14;     // it=0: pm=lane, always valid
        const float* px = ximg + r * 56 + cl * 2;
        top = *(const float2*)px;
        bot = *(const float2*)(px + 28);
    }

#pragma unroll 1
    for (int it = 0; it < 4; ++it) {
        // prefetch next iteration's pixels
        float2 ntop = top, nbot = bot;
        if (it < 3) {
            const int pmn = (it + 1) * 64 + lane;
            const int pcn = (pmn < N_PATCH) ? pmn : N_PATCH - 1;
            const int r = pcn / 14, cl = pcn - r * 14;
            const float* px = ximg + r * 56 + cl * 2;
            ntop = *(const float2*)px;
            nbot = *(const float2*)(px + 28);
        }

        const int pm   = it * 64 + lane;
        const bool vld = (pm < N_PATCH);

        const float c0 = __cosf(0.5f * top.x), s0 = __sinf(0.5f * top.x);
        const float c1 = __cosf(0.5f * top.y), s1 = __sinf(0.5f * top.y);
        const float c2 = __cosf(0.5f * bot.x), s2 = __sinf(0.5f * bot.x);
        const float c3 = __cosf(0.5f * bot.y), s3 = __sinf(0.5f * bot.y);

        const float wm = vld ? 1.f : 0.f;     // zero st => zero amp/meas for dead slots
        const float p00 = wm * c0 * c1, p01 = wm * c0 * s1;
        const float p10 = wm * s0 * c1, p11 = wm * s0 * s1;
        const float q00 = c2 * c3, q01 = c2 * s3, q10 = s2 * c3, q11 = s2 * s3;
        float st[16];
        st[ 0]=p00*q00; st[ 1]=p00*q01; st[ 2]=p00*q10; st[ 3]=p00*q11;
        st[ 4]=p01*q00; st[ 5]=p01*q01; st[ 6]=p01*q10; st[ 7]=p01*q11;
        st[ 8]=p10*q00; st[ 9]=p10*q01; st[10]=p10*q10; st[11]=p10*q11;
        st[12]=p11*q00; st[13]=p11*q01; st[14]=p11*q10; st[15]=p11*q11;

        // ---- exact split st = hi + lo, pack to bf16, stage to LDS ----
        // no explicit lgkmcnt fences: DS ops are in-order within a wave, the
        // compiler auto-waits lgkmcnt before consuming ds_read results, and
        // it cannot reorder aliasing sB accesses. No inter-wave LDS sharing.
        I4S8 h0, h1, l0, l1;
#pragma unroll
        for (int j = 0; j < 8; ++j) {
            const unsigned b0 = __float_as_uint(st[2*j]);
            const unsigned b1 = __float_as_uint(st[2*j+1]);
            const unsigned hp = __builtin_amdgcn_perm(b1, b0, 0x07060302u);
            const unsigned lb0 = __float_as_uint(st[2*j]   - __uint_as_float(b0 & 0xffff0000u));
            const unsigned lb1 = __float_as_uint(st[2*j+1] - __uint_as_float(b1 & 0xffff0000u));
            const unsigned lp = __builtin_amdgcn_perm(lb1, lb0, 0x07060302u);
            if (j < 4) { h0.i[j] = (int)hp; l0.i[j] = (int)lp; }
            else       { h1.i[j-4] = (int)hp; l1.i[j-4] = (int)lp; }
        }
        *(short8*)&sB[w][lane][ 0] = h0.v;   // k  0..7  (hi d0..7)
        *(short8*)&sB[w][lane][ 8] = h1.v;   // k  8..15 (hi d8..15)
        *(short8*)&sB[w][lane][16] = l0.v;   // k 16..23 (lo d0..7)
        *(short8*)&sB[w][lane][24] = l1.v;   // k 24..31 (lo d8..15)

        // ---- 4 groups of 16 patches: 2 MFMAs, partial Walsh, direct fold ----
#pragma unroll
        for (int g = 0; g < 4; ++g) {
            const int q = 16 * g + colc;                       // local patch (column)
            const short8 bf = *(const short8*)&sB[w][q][8 * kb];  // my k-slice

            f32x4 amv = {0.f, 0.f, 0.f, 0.f};
            amv = __builtin_amdgcn_mfma_f32_16x16x32_bf16(a1, bf, amv, 0, 0, 0);
            amv = __builtin_amdgcn_mfma_f32_16x16x32_bf16(a2, bf, amv, 0, 0, 0);

            // lane holds amp[e] for e = 4*kb + reg, patch = it*64 + q
            const float sq0 = amv[0]*amv[0], sq1 = amv[1]*amv[1];
            const float sq2 = amv[2]*amv[2], sq3 = amv[3]*amv[3];
            const float t01 = sq0 + sq1, t23 = sq2 + sq3, sall = t01 + t23;
            const float m0 = sgn0 * sall;                    // wire0 partial (this kb)
            const float m1 = sgn1 * sall;                    // wire1 partial
            const float m2 = t01 - t23;                      // wire2 partial
            const float m3 = (sq0 - sq1) + (sq2 - sq3);      // wire3 partial

            // fold PARTIAL m's into logits — no shuffles here; the final
            // 64-lane butterfly sums over both colc (xor 1..8) and kb (xor 16,32).
            const int pg  = it * 64 + q;
            const int pcl = (pg < N_PATCH) ? pg : N_PATCH - 1; // m's are 0 when invalid
#pragma unroll
            for (int c = 0; c < NCLS; ++c) {
                const float4 wv = *(const float4*)&W[c * FEAT + 4 * pcl];
                acc[c] = fmaf(m0, wv.x, fmaf(m1, wv.y, fmaf(m2, wv.z, fmaf(m3, wv.w, acc[c]))));
            }
        }

        top = ntop; bot = nbot;
    }

    // ---- full 64-lane logit reduction (16 columns x 4 k-blocks) ----
#pragma unroll
    for (int c = 0; c < NCLS; ++c) {
        float v = acc[c];
        v += __shfl_xor(v,  1, 64);
        v += __shfl_xor(v,  2, 64);
        v += __shfl_xor(v,  4, 64);
        v += __shfl_xor(v,  8, 64);
        v += __shfl_xor(v, 16, 64);
        v += __shfl_xor(v, 32, 64);
        acc[c] = v + b[c];
    }

    // ---- log_softmax ----
    float m = acc[0];
#pragma unroll
    for (int c = 1; c < NCLS; ++c) m = fmaxf(m, acc[c]);
    float ssum = 0.f;
#pragma unroll
    for (int c = 0; c < NCLS; ++c) ssum += __expf(acc[c] - m);
    const float ls = __logf(ssum);

    float v = 0.f;
#pragma unroll
    for (int c = 0; c < NCLS; ++c) if (lane == c) v = acc[c];
    if (lane < NCLS)
        out[(size_t)img * NCLS + lane] = v - m - ls;
}

extern "C" void kernel_launch(void* const* d_in, const int* in_sizes, int n_in,
                              void* d_out, int out_size, void* d_ws, size_t ws_size,
                              hipStream_t stream) {
    const float* x = (const float*)d_in[0];
    const float* U = (const float*)d_in[1];
    const float* W = (const float*)d_in[2];
    const float* b = (const float*)d_in[3];
    float* out = (float*)d_out;

    const int n_img = in_sizes[0] / FEAT;            // 8192
    const int grid  = (n_img + WPB - 1) / WPB;       // 2048 blocks = 8 per CU

    quanv_mfma_kernel<<<grid, THREADS, 0, stream>>>(x, U, W, b, out, n_img);
}

// Round 13
// 117.378 us; speedup vs baseline: 1.0281x; 1.0281x over previous
//
#include <hip/hip_runtime.h>

typedef __attribute__((ext_vector_type(8))) short short8;   // 8 bf16 = 4 VGPRs
typedef __attribute__((ext_vector_type(4))) float f32x4;

#define THREADS 256
#define WPB 4            // waves per block = images per block
#define N_PATCH 196
#define NCLS 10
#define FEAT 784
#define ROWSH 40         // ushorts per LDS row = 80 B (20 dwords, 16B-aligned)

union I4S8 { int i[4]; short8 v; };

// (256,8) forced VGPR<64 -> 17.6 MB scratch spills (round 11). (256,6) gives
// an ~85-reg budget: no spills, still 6+ waves/SIMD of latency hiding.
__global__ __launch_bounds__(THREADS, 6)
void quanv_mfma_kernel(const float* __restrict__ x,
                       const float* __restrict__ U,
                       const float* __restrict__ W,
                       const float* __restrict__ b,
                       float* __restrict__ out, int n_img)
{
    // [wave][local patch 0..63][k 0..31 bf16 (+pad)]  k = [hi(d0..15) | lo(d0..15)]
    __shared__ unsigned short sB[WPB][64][ROWSH];      // 20 KB/block

    const int t    = threadIdx.x;
    const int w    = t >> 6;
    const int lane = t & 63;
    const int img  = blockIdx.x * WPB + w;
    if (img >= n_img) return;                 // no barriers anywhere in kernel

    const int colc = lane & 15;               // MFMA column (patch-in-group) / A row owner
    const int kb   = lane >> 4;               // k-block 0..3
    const float sgn0 = (kb & 2) ? -1.f : 1.f; // sign of e bit3 (wire 0, MSB): e = 4*kb+reg
    const float sgn1 = (kb & 1) ? -1.f : 1.f; // sign of e bit2 (wire 1)

    // ---- A fragments from U, loaded ONCE ----
    // A1 = [Uhi | Uhi], A2 = [Ulo | 0]  (16x32 each, K-blocked by lane>>4)
    short8 a1, a2;
    {
        const float* Urow = U + colc * 16 + (kb & 1) * 8;
        unsigned ub[8]; float uf[8];
#pragma unroll
        for (int i = 0; i < 8; ++i) { uf[i] = Urow[i]; ub[i] = __float_as_uint(uf[i]); }
        I4S8 hi, lo;
#pragma unroll
        for (int j = 0; j < 4; ++j)
            hi.i[j] = (int)__builtin_amdgcn_perm(ub[2*j+1], ub[2*j], 0x07060302u);
#pragma unroll
        for (int j = 0; j < 4; ++j) {
            unsigned lb0 = __float_as_uint(uf[2*j]   - __uint_as_float(ub[2*j]   & 0xffff0000u));
            unsigned lb1 = __float_as_uint(uf[2*j+1] - __uint_as_float(ub[2*j+1] & 0xffff0000u));
            lo.i[j] = (kb < 2) ? (int)__builtin_amdgcn_perm(lb1, lb0, 0x07060302u) : 0;
        }
        a1 = hi.v; a2 = lo.v;
    }

    const float* ximg = x + (size_t)img * FEAT;

    float acc[NCLS];
#pragma unroll
    for (int c = 0; c < NCLS; ++c) acc[c] = 0.f;

    // 1-deep pixel prefetch (global latency hides under previous iteration)
    float2 top, bot;
    {
        const int r = lane / 14, cl = lane - r * 14;     // it=0: pm=lane, always valid
        const float* px = ximg + r * 56 + cl * 2;
        top = *(const float2*)px;
        bot = *(const float2*)(px + 28);
    }

#pragma unroll 1
    for (int it = 0; it < 4; ++it) {
        // prefetch next iteration's pixels
        float2 ntop = top, nbot = bot;
        if (it < 3) {
            const int pmn = (it + 1) * 64 + lane;
            const int pcn = (pmn < N_PATCH) ? pmn : N_PATCH - 1;
            const int r = pcn / 14, cl = pcn - r * 14;
            const float* px = ximg + r * 56 + cl * 2;
            ntop = *(const float2*)px;
            nbot = *(const float2*)(px + 28);
        }

        const int pm   = it * 64 + lane;
        const bool vld = (pm < N_PATCH);

        const float c0 = __cosf(0.5f * top.x), s0 = __sinf(0.5f * top.x);
        const float c1 = __cosf(0.5f * top.y), s1 = __sinf(0.5f * top.y);
        const float c2 = __cosf(0.5f * bot.x), s2 = __sinf(0.5f * bot.x);
        const float c3 = __cosf(0.5f * bot.y), s3 = __sinf(0.5f * bot.y);

        const float wm = vld ? 1.f : 0.f;     // zero st => zero amp/meas for dead slots
        const float p00 = wm * c0 * c1, p01 = wm * c0 * s1;
        const float p10 = wm * s0 * c1, p11 = wm * s0 * s1;
        const float q00 = c2 * c3, q01 = c2 * s3, q10 = s2 * c3, q11 = s2 * s3;
        float st[16];
        st[ 0]=p00*q00; st[ 1]=p00*q01; st[ 2]=p00*q10; st[ 3]=p00*q11;
        st[ 4]=p01*q00; st[ 5]=p01*q01; st[ 6]=p01*q10; st[ 7]=p01*q11;
        st[ 8]=p10*q00; st[ 9]=p10*q01; st[10]=p10*q10; st[11]=p10*q11;
        st[12]=p11*q00; st[13]=p11*q01; st[14]=p11*q10; st[15]=p11*q11;

        // ---- exact split st = hi + lo, pack to bf16, stage to LDS ----
        // no explicit lgkmcnt fences: DS ops are in-order within a wave, the
        // compiler auto-waits lgkmcnt before consuming ds_read results, and
        // it cannot reorder aliasing sB accesses. No inter-wave LDS sharing.
        I4S8 h0, h1, l0, l1;
#pragma unroll
        for (int j = 0; j < 8; ++j) {
            const unsigned b0 = __float_as_uint(st[2*j]);
            const unsigned b1 = __float_as_uint(st[2*j+1]);
            const unsigned hp = __builtin_amdgcn_perm(b1, b0, 0x07060302u);
            const unsigned lb0 = __float_as_uint(st[2*j]   - __uint_as_float(b0 & 0xffff0000u));
            const unsigned lb1 = __float_as_uint(st[2*j+1] - __uint_as_float(b1 & 0xffff0000u));
            const unsigned lp = __builtin_amdgcn_perm(lb1, lb0, 0x07060302u);
            if (j < 4) { h0.i[j] = (int)hp; l0.i[j] = (int)lp; }
            else       { h1.i[j-4] = (int)hp; l1.i[j-4] = (int)lp; }
        }
        *(short8*)&sB[w][lane][ 0] = h0.v;   // k  0..7  (hi d0..7)
        *(short8*)&sB[w][lane][ 8] = h1.v;   // k  8..15 (hi d8..15)
        *(short8*)&sB[w][lane][16] = l0.v;   // k 16..23 (lo d0..7)
        *(short8*)&sB[w][lane][24] = l1.v;   // k 24..31 (lo d8..15)

        // ---- 4 groups of 16 patches: 2 MFMAs, partial Walsh, direct fold ----
#pragma unroll
        for (int g = 0; g < 4; ++g) {
            const int q = 16 * g + colc;                       // local patch (column)
            const short8 bf = *(const short8*)&sB[w][q][8 * kb];  // my k-slice

            f32x4 amv = {0.f, 0.f, 0.f, 0.f};
            amv = __builtin_amdgcn_mfma_f32_16x16x32_bf16(a1, bf, amv, 0, 0, 0);
            amv = __builtin_amdgcn_mfma_f32_16x16x32_bf16(a2, bf, amv, 0, 0, 0);

            // lane holds amp[e] for e = 4*kb + reg, patch = it*64 + q
            const float sq0 = amv[0]*amv[0], sq1 = amv[1]*amv[1];
            const float sq2 = amv[2]*amv[2], sq3 = amv[3]*amv[3];
            const float t01 = sq0 + sq1, t23 = sq2 + sq3, sall = t01 + t23;
            const float m0 = sgn0 * sall;                    // wire0 partial (this kb)
            const float m1 = sgn1 * sall;                    // wire1 partial
            const float m2 = t01 - t23;                      // wire2 partial
            const float m3 = (sq0 - sq1) + (sq2 - sq3);      // wire3 partial

            // fold PARTIAL m's into logits — no shuffles here; the final
            // 64-lane butterfly sums over both colc (xor 1..8) and kb (xor 16,32).
            const int pg  = it * 64 + q;
            const int pcl = (pg < N_PATCH) ? pg : N_PATCH - 1; // m's are 0 when invalid
#pragma unroll
            for (int c = 0; c < NCLS; ++c) {
                const float4 wv = *(const float4*)&W[c * FEAT + 4 * pcl];
                acc[c] = fmaf(m0, wv.x, fmaf(m1, wv.y, fmaf(m2, wv.z, fmaf(m3, wv.w, acc[c]))));
            }
        }

        top = ntop; bot = nbot;
    }

    // ---- full 64-lane logit reduction (16 columns x 4 k-blocks) ----
#pragma unroll
    for (int c = 0; c < NCLS; ++c) {
        float v = acc[c];
        v += __shfl_xor(v,  1, 64);
        v += __shfl_xor(v,  2, 64);
        v += __shfl_xor(v,  4, 64);
        v += __shfl_xor(v,  8, 64);
        v += __shfl_xor(v, 16, 64);
        v += __shfl_xor(v, 32, 64);
        acc[c] = v + b[c];
    }

    // ---- log_softmax ----
    float m = acc[0];
#pragma unroll
    for (int c = 1; c < NCLS; ++c) m = fmaxf(m, acc[c]);
    float ssum = 0.f;
#pragma unroll
    for (int c = 0; c < NCLS; ++c) ssum += __expf(acc[c] - m);
    const float ls = __logf(ssum);

    float v = 0.f;
#pragma unroll
    for (int c = 0; c < NCLS; ++c) if (lane == c) v = acc[c];
    if (lane < NCLS)
        out[(size_t)img * NCLS + lane] = v - m - ls;
}

extern "C" void kernel_launch(void* const* d_in, const int* in_sizes, int n_in,
                              void* d_out, int out_size, void* d_ws, size_t ws_size,
                              hipStream_t stream) {
    const float* x = (const float*)d_in[0];
    const float* U = (const float*)d_in[1];
    const float* W = (const float*)d_in[2];
    const float* b = (const float*)d_in[3];
    float* out = (float*)d_out;

    const int n_img = in_sizes[0] / FEAT;            // 8192
    const int grid  = (n_img + WPB - 1) / WPB;       // 2048 blocks

    quanv_mfma_kernel<<<grid, THREADS, 0, stream>>>(x, U, W, b, out, n_img);
}

// Round 15
// 92.357 us; speedup vs baseline: 1.3066x; 1.2709x over previous
//
#include <hip/hip_runtime.h>

typedef __attribute__((ext_vector_type(8))) short short8;   // 8 bf16 = 4 VGPRs
typedef __attribute__((ext_vector_type(4))) float f32x4;

#define THREADS 256
#define WPB 4            // waves per block = images per block
#define N_PATCH 196
#define NCLS 10
#define FEAT 784
#define ROWSH 40         // ushorts per LDS row = 80 B

union I4S8 { int i[4]; short8 v; };

// Max-threads bound only: r11/r13 showed min-waves bounds make the allocator
// clamp to 32-36 VGPR and serialize the inner loop (both pipes <50% busy).
__global__ __launch_bounds__(THREADS)
void quanv_mfma_kernel(const float* __restrict__ x,
                       const float* __restrict__ U,
                       const float* __restrict__ W,
                       const float* __restrict__ b,
                       float* __restrict__ out, int n_img)
{
    __shared__ unsigned short sB[WPB][64][ROWSH];   // 20 KB staging
    __shared__ float sLog[WPB][16];                 // per-wave logit exchange

    const int t    = threadIdx.x;
    const int w    = t >> 6;
    const int lane = t & 63;
    const int img  = blockIdx.x * WPB + w;
    if (img >= n_img) return;                 // no inter-wave sync anywhere

    const int colc = lane & 15;               // MFMA column / A row owner
    const int kb   = lane >> 4;               // k-block 0..3
    const float sgn0 = (kb & 2) ? -1.f : 1.f; // e bit3 (wire 0) sign, e = 4*kb+reg
    const float sgn1 = (kb & 1) ? -1.f : 1.f; // e bit2 (wire 1) sign
    // class split across kb-groups: {0,1,2} {3,4,5} {6,7} {8,9}
    const int cbase = (kb < 2) ? 3 * kb : (6 + 2 * (kb - 2));
    const int ccnt  = (kb < 2) ? 3 : 2;

    // ---- A fragments from U, loaded ONCE: A1=[Uhi|Uhi], A2=[Ulo|0] ----
    short8 a1, a2;
    {
        const float* Urow = U + colc * 16 + (kb & 1) * 8;
        unsigned ub[8]; float uf[8];
#pragma unroll
        for (int i = 0; i < 8; ++i) { uf[i] = Urow[i]; ub[i] = __float_as_uint(uf[i]); }
        I4S8 hi, lo;
#pragma unroll
        for (int j = 0; j < 4; ++j)
            hi.i[j] = (int)__builtin_amdgcn_perm(ub[2*j+1], ub[2*j], 0x07060302u);
#pragma unroll
        for (int j = 0; j < 4; ++j) {
            unsigned lb0 = __float_as_uint(uf[2*j]   - __uint_as_float(ub[2*j]   & 0xffff0000u));
            unsigned lb1 = __float_as_uint(uf[2*j+1] - __uint_as_float(ub[2*j+1] & 0xffff0000u));
            lo.i[j] = (kb < 2) ? (int)__builtin_amdgcn_perm(lb1, lb0, 0x07060302u) : 0;
        }
        a1 = hi.v; a2 = lo.v;
    }

    const float* ximg = x + (size_t)img * FEAT;

    float accl[3] = {0.f, 0.f, 0.f};          // my 2-3 classes only

    // 1-deep pixel prefetch
    float2 top, bot;
    {
        const int r = lane / 14, cl = lane - r * 14;   // it=0 always valid
        const float* px = ximg + r * 56 + cl * 2;
        top = *(const float2*)px;
        bot = *(const float2*)(px + 28);
    }

#pragma unroll 1
    for (int it = 0; it < 4; ++it) {
        float2 ntop = top, nbot = bot;
        if (it < 3) {
            const int pmn = (it + 1) * 64 + lane;
            const int pcn = (pmn < N_PATCH) ? pmn : N_PATCH - 1;
            const int r = pcn / 14, cl = pcn - r * 14;
            const float* px = ximg + r * 56 + cl * 2;
            ntop = *(const float2*)px;
            nbot = *(const float2*)(px + 28);
        }

        const bool vld = (it * 64 + lane < N_PATCH);

        const float c0 = __cosf(0.5f * top.x), s0 = __sinf(0.5f * top.x);
        const float c1 = __cosf(0.5f * top.y), s1 = __sinf(0.5f * top.y);
        const float c2 = __cosf(0.5f * bot.x), s2 = __sinf(0.5f * bot.x);
        const float c3 = __cosf(0.5f * bot.y), s3 = __sinf(0.5f * bot.y);

        const float wm = vld ? 1.f : 0.f;     // zero st for dead slots
        const float p00 = wm * c0 * c1, p01 = wm * c0 * s1;
        const float p10 = wm * s0 * c1, p11 = wm * s0 * s1;
        const float q00 = c2 * c3, q01 = c2 * s3, q10 = s2 * c3, q11 = s2 * s3;
        float st[16];
        st[ 0]=p00*q00; st[ 1]=p00*q01; st[ 2]=p00*q10; st[ 3]=p00*q11;
        st[ 4]=p01*q00; st[ 5]=p01*q01; st[ 6]=p01*q10; st[ 7]=p01*q11;
        st[ 8]=p10*q00; st[ 9]=p10*q01; st[10]=p10*q10; st[11]=p10*q11;
        st[12]=p11*q00; st[13]=p11*q01; st[14]=p11*q10; st[15]=p11*q11;

        // exact split st = hi + lo, pack, stage (in-order DS, wave-private slice)
        I4S8 h0, h1, l0, l1;
#pragma unroll
        for (int j = 0; j < 8; ++j) {
            const unsigned b0 = __float_as_uint(st[2*j]);
            const unsigned b1 = __float_as_uint(st[2*j+1]);
            const unsigned hp = __builtin_amdgcn_perm(b1, b0, 0x07060302u);
            const unsigned lb0 = __float_as_uint(st[2*j]   - __uint_as_float(b0 & 0xffff0000u));
            const unsigned lb1 = __float_as_uint(st[2*j+1] - __uint_as_float(b1 & 0xffff0000u));
            const unsigned lp = __builtin_amdgcn_perm(lb1, lb0, 0x07060302u);
            if (j < 4) { h0.i[j] = (int)hp; l0.i[j] = (int)lp; }
            else       { h1.i[j-4] = (int)hp; l1.i[j-4] = (int)lp; }
        }
        *(short8*)&sB[w][lane][ 0] = h0.v;
        *(short8*)&sB[w][lane][ 8] = h1.v;
        *(short8*)&sB[w][lane][16] = l0.v;
        *(short8*)&sB[w][lane][24] = l1.v;

        // ---- all 4 fragments up front, 8 MFMAs into 4 independent accs ----
        const short8 bf0 = *(const short8*)&sB[w][ 0 + colc][8 * kb];
        const short8 bf1 = *(const short8*)&sB[w][16 + colc][8 * kb];
        const short8 bf2 = *(const short8*)&sB[w][32 + colc][8 * kb];
        const short8 bf3 = *(const short8*)&sB[w][48 + colc][8 * kb];

        f32x4 v0 = {0.f,0.f,0.f,0.f}, v1 = v0, v2 = v0, v3 = v0;
        v0 = __builtin_amdgcn_mfma_f32_16x16x32_bf16(a1, bf0, v0, 0, 0, 0);
        v1 = __builtin_amdgcn_mfma_f32_16x16x32_bf16(a1, bf1, v1, 0, 0, 0);
        v2 = __builtin_amdgcn_mfma_f32_16x16x32_bf16(a1, bf2, v2, 0, 0, 0);
        v3 = __builtin_amdgcn_mfma_f32_16x16x32_bf16(a1, bf3, v3, 0, 0, 0);
        v0 = __builtin_amdgcn_mfma_f32_16x16x32_bf16(a2, bf0, v0, 0, 0, 0);
        v1 = __builtin_amdgcn_mfma_f32_16x16x32_bf16(a2, bf1, v1, 0, 0, 0);
        v2 = __builtin_amdgcn_mfma_f32_16x16x32_bf16(a2, bf2, v2, 0, 0, 0);
        v3 = __builtin_amdgcn_mfma_f32_16x16x32_bf16(a2, bf3, v3, 0, 0, 0);

        // ---- per group: partial walsh -> kb-reduce (2 shfl) -> split fold ----
#pragma unroll
        for (int g = 0; g < 4; ++g) {
            const f32x4 amv = (g == 0) ? v0 : (g == 1) ? v1 : (g == 2) ? v2 : v3;
            const float sq0 = amv[0]*amv[0], sq1 = amv[1]*amv[1];
            const float sq2 = amv[2]*amv[2], sq3 = amv[3]*amv[3];
            const float t01 = sq0 + sq1, t23 = sq2 + sq3, sall = t01 + t23;
            float m0 = sgn0 * sall;
            float m1 = sgn1 * sall;
            float m2 = t01 - t23;
            float m3 = (sq0 - sq1) + (sq2 - sq3);

            // full m's: sum over the 4 k-blocks
            m0 += __shfl_xor(m0, 16, 64); m0 += __shfl_xor(m0, 32, 64);
            m1 += __shfl_xor(m1, 16, 64); m1 += __shfl_xor(m1, 32, 64);
            m2 += __shfl_xor(m2, 16, 64); m2 += __shfl_xor(m2, 32, 64);
            m3 += __shfl_xor(m3, 16, 64); m3 += __shfl_xor(m3, 32, 64);

            const int pg  = it * 64 + 16 * g + colc;
            const int pcl = (pg < N_PATCH) ? pg : N_PATCH - 1;  // m's are 0 there
#pragma unroll
            for (int cc = 0; cc < 3; ++cc) {
                const int  c     = cbase + cc;
                const bool cval  = (cc < ccnt);
                const int  cSafe = (c < NCLS) ? c : NCLS - 1;
                const float4 wv = *(const float4*)&W[cSafe * FEAT + 4 * pcl];
                const float contrib = m0*wv.x + m1*wv.y + m2*wv.z + m3*wv.w;
                accl[cc] += cval ? contrib : 0.f;
            }
        }

        top = ntop; bot = nbot;
    }

    // ---- reduce my classes over colc (within kb-group) ----
#pragma unroll
    for (int cc = 0; cc < 3; ++cc) {
        float v = accl[cc];
        v += __shfl_xor(v, 1, 64);
        v += __shfl_xor(v, 2, 64);
        v += __shfl_xor(v, 4, 64);
        v += __shfl_xor(v, 8, 64);
        accl[cc] = v;
    }

    // one lane per kb-group publishes its classes (intra-wave, in-order DS)
    if (colc == 0) {
#pragma unroll
        for (int cc = 0; cc < 3; ++cc)
            if (cc < ccnt) sLog[w][cbase + cc] = accl[cc] + b[cbase + cc];
    }
    asm volatile("s_waitcnt lgkmcnt(0)" ::: "memory");

    float lg[NCLS];
#pragma unroll
    for (int c = 0; c < NCLS; ++c) lg[c] = sLog[w][c];

    float m = lg[0];
#pragma unroll
    for (int c = 1; c < NCLS; ++c) m = fmaxf(m, lg[c]);
    float ssum = 0.f;
#pragma unroll
    for (int c = 0; c < NCLS; ++c) ssum += __expf(lg[c] - m);
    const float ls = __logf(ssum);

    if (lane < NCLS)
        out[(size_t)img * NCLS + lane] = lg[lane] - m - ls;
}

extern "C" void kernel_launch(void* const* d_in, const int* in_sizes, int n_in,
                              void* d_out, int out_size, void* d_ws, size_t ws_size,
                              hipStream_t stream) {
    const float* x = (const float*)d_in[0];
    const float* U = (const float*)d_in[1];
    const float* W = (const float*)d_in[2];
    const float* b = (const float*)d_in[3];
    float* out = (float*)d_out;

    const int n_img = in_sizes[0] / FEAT;            // 8192
    const int grid  = (n_img + WPB - 1) / WPB;       // 2048 blocks

    quanv_mfma_kernel<<<grid, THREADS, 0, stream>>>(x, U, W, b, out, n_img);
}